// Round 1
// baseline (997.873 us; speedup 1.0000x reference)
//
#include <hip/hip_runtime.h>

// DGP-RF embeddings, fused MFMA. Round 9: occupancy.
// R8 analysis: MfmaUtil 19.5% + VALUBusy 36% -> 44% of cycles NO pipe issues.
// Loop is GEMM1 -> barrier -> moments -> barrier -> GEMM2 (serial per block),
// and LDS (69.6KB) caps us at 2 blocks/CU = 8 waves/CU (2/SIMD): nothing to
// fill the barrier/latency bubbles. Fix: MT 64 -> 32. LDS halves to ~34.8KB
// -> 4 blocks/CU = 16 waves/CU; acc arrays halve so VGPR drops too
// (__launch_bounds__(256,4)). All totals (FLOPs, LDS bytes, atomics, X HBM)
// unchanged; only W1/W2 L2 re-reads double (2.4->4.8GB ~ 13 TB/s << 34.5
// ceiling). Predicted: Occupancy ~45%, Mfma ~30%, VALU ~55%, fused ~360-400us.
// (Bank conflicts ~2.1e7 stay; swizzle is the round-10 lever if needed.)

#define NPTS   131072
#define SGRP   16384
#define DIN    256
#define NRF    1024
#define DOUT   128
#define MT     32            // points per WG  (R9: was 64)
#define NMT    (MT / 16)     // 16-row point blocks per WG
#define NWG    (NPTS / MT)   // 4096

#define XLD    264   // bf16 X row stride
#define XQLD   264   // fp8 x^2 row stride
#define TMLD   72    // bf16 m' row stride
#define TVLD   72    // fp8 v'/m'^2 row stride

typedef unsigned short ushort_t;
typedef unsigned char  uchar_t;
typedef __attribute__((ext_vector_type(8))) short bf16x8;
typedef __attribute__((ext_vector_type(4))) float f32x4;
typedef __attribute__((ext_vector_type(4))) float f32x4v;

__device__ __forceinline__ unsigned short f2bf(float f) {
  unsigned u = __float_as_uint(f);
  u += 0x7fffu + ((u >> 16) & 1u);   // round-to-nearest-even
  return (unsigned short)(u >> 16);
}

// pack 2 floats -> 2 fp8 e4m3 bytes into (HI? bytes 2,3 : bytes 0,1) of old
template <bool HI>
__device__ __forceinline__ unsigned cvt2_fp8(float a, float b, unsigned old) {
#if __has_builtin(__builtin_amdgcn_cvt_pk_fp8_f32)
  return __builtin_amdgcn_cvt_pk_fp8_f32(a, b, old, HI);
#else
  auto enc = [](float x) -> unsigned {
    if (!(x > 0.00097656f)) return 0u;
    if (x >= 448.f) return 0x7Eu;
    union { float f; unsigned u; } v; v.f = x;
    int e = (int)(v.u >> 23) - 127;
    if (e < -6) { int n = (int)(x * 512.f + 0.5f); return (unsigned)n; }
    v.u += 0x0007FFFFu + ((v.u >> 20) & 1u);
    e = (int)(v.u >> 23) - 127;
    if (e > 8) return 0x7Eu;
    return (unsigned)(((e + 7) << 3) | ((v.u >> 20) & 7u));
  };
  unsigned p = (enc(a) | (enc(b) << 8));
  return HI ? ((old & 0x0000ffffu) | (p << 16)) : ((old & 0xffff0000u) | p);
#endif
}

__device__ __forceinline__ float fast_rcp(float x) {
#if __has_builtin(__builtin_amdgcn_rcpf)
  return __builtin_amdgcn_rcpf(x);
#else
  return 1.0f / x;
#endif
}
__device__ __forceinline__ float fast_rsq(float x) {
#if __has_builtin(__builtin_amdgcn_rsqf)
  return __builtin_amdgcn_rsqf(x);
#else
  return rsqrtf(x);
#endif
}
__device__ __forceinline__ float fast_exp2(float x) {
#if __has_builtin(__builtin_amdgcn_exp2f)
  return __builtin_amdgcn_exp2f(x);
#else
  return exp2f(x);
#endif
}

// Exact Gaussian-ReLU moments (A&S 7.1.26 erf, one shared exp2).
__device__ __forceinline__ void relu_moments(float mu, float v,
                                             float& mo, float& vo) {
  float vpe = v + 1e-8f;
  float rsq = fast_rsq(vpe);
  float s   = vpe * rsq;
  float z   = mu * rsq;
  float E   = fast_exp2(-0.7213475204444817f * z * z);  // exp(-z^2/2)
  float x   = 0.70710678118654752f * fabsf(z);
  float t   = fast_rcp(fmaf(0.3275911f, x, 1.0f));
  float poly = t * fmaf(t, fmaf(t, fmaf(t, fmaf(t, 1.061405429f, -1.453152027f),
                                        1.421413741f), -0.284496736f), 0.254829592f);
  float q   = 0.5f * poly * E;
  float Phi = (z >= 0.0f) ? (1.0f - q) : q;
  float phi = 0.3989422804014327f * E;
  float sphi = s * phi;
  mo = fmaf(mu, Phi, sphi);
  float ey2 = fmaf(fmaf(mu, mu, v), Phi, mu * sphi);
  vo = fmaxf(fmaf(-mo, mo, ey2), 1e-6f);
}

// ---------------- kernel 0: detect whether X_idx is int32 or int64 -------------
__global__ void detect_idx_kernel(const unsigned* __restrict__ raw,
                                  int* __restrict__ flag) {
  __shared__ int any_nz;
  if (threadIdx.x == 0) any_nz = 0;
  __syncthreads();
  if (raw[2 * threadIdx.x + 1] != 0u) atomicOr(&any_nz, 1);
  __syncthreads();
  if (threadIdx.x == 0) *flag = (any_nz == 0) ? 1 : 0;   // 1 => int64
}

// ---------------- kernel 1: convert weights (bf16 mean path, fp8 var path) ----
__global__ __launch_bounds__(256) void convert_kernel(
    const float* __restrict__ W1mu, const float* __restrict__ W1var,
    const float* __restrict__ W2mu, const float* __restrict__ W2var,
    ushort_t* __restrict__ w1mu_bf, uchar_t* __restrict__ w1var8,
    ushort_t* __restrict__ w2mu_bf, uchar_t* __restrict__ w2b8,
    uchar_t* __restrict__ w2var8) {
  int i4 = (blockIdx.x * 256 + threadIdx.x) * 4;   // grid covers 262144
  {
    f32x4v m = *(const f32x4v*)(W1mu + i4);
    ushort4 b; b.x = f2bf(m[0]); b.y = f2bf(m[1]); b.z = f2bf(m[2]); b.w = f2bf(m[3]);
    *(ushort4*)(w1mu_bf + i4) = b;
    f32x4v v = *(const f32x4v*)(W1var + i4);
    unsigned p = cvt2_fp8<false>(v[0] * 256.f, v[1] * 256.f, 0u);
    p = cvt2_fp8<true>(v[2] * 256.f, v[3] * 256.f, p);
    *(unsigned*)(w1var8 + i4) = p;
  }
  if (i4 < NRF * DOUT) {
    f32x4v m = *(const f32x4v*)(W2mu + i4);
    f32x4v v = *(const f32x4v*)(W2var + i4);
    ushort4 b; b.x = f2bf(m[0]); b.y = f2bf(m[1]); b.z = f2bf(m[2]); b.w = f2bf(m[3]);
    *(ushort4*)(w2mu_bf + i4) = b;
    unsigned pb = cvt2_fp8<false>(fmaf(m[0], m[0], v[0]) * 256.f,
                                  fmaf(m[1], m[1], v[1]) * 256.f, 0u);
    pb = cvt2_fp8<true>(fmaf(m[2], m[2], v[2]) * 256.f,
                        fmaf(m[3], m[3], v[3]) * 256.f, pb);
    *(unsigned*)(w2b8 + i4) = pb;
    unsigned pv = cvt2_fp8<false>(v[0] * 256.f, v[1] * 256.f, 0u);
    pv = cvt2_fp8<true>(v[2] * 256.f, v[3] * 256.f, pv);
    *(unsigned*)(w2var8 + i4) = pv;
  }
}

// ---------------- kernel 2: fused DGP-RF block --------------------------------
__global__ __launch_bounds__(256, 4) void fused_kernel(
    const float* __restrict__ X,
    const unsigned* __restrict__ Xidx_raw,
    const ushort_t* __restrict__ W1mu, const uchar_t* __restrict__ W1var8,
    const ushort_t* __restrict__ W2mu, const uchar_t* __restrict__ W2b8,
    const uchar_t* __restrict__ W2var8,
    const int* __restrict__ flag64,
    float* __restrict__ acc_means, float* __restrict__ acc_vars) {
  __shared__ ushort_t Xb[MT * XLD];    // 16.9 KB bf16 x
  __shared__ uchar_t  Xq8[MT * XQLD];  //  8.4 KB fp8 x^2
  __shared__ ushort_t Tm[MT * TMLD];   //  4.6 KB bf16 m'
  __shared__ uchar_t  Tv8[MT * TVLD];  //  2.3 KB fp8 v'
  __shared__ uchar_t  T38[MT * TVLD];  //  2.3 KB fp8 m'^2
  __shared__ int sidx[MT];

  const int tid = threadIdx.x;
  const int p0  = blockIdx.x * MT;
  const int is64 = *flag64;

  if (tid < MT) {
    int p = p0 + tid;
    sidx[tid] = (int)(is64 ? Xidx_raw[2 * (size_t)p] : Xidx_raw[p]);
  }
  // stage X tile: bf16 x and fp8 x^2, converted once here
#pragma unroll
  for (int i = 0; i < MT / 4; ++i) {
    int idx4 = i * 256 + tid;       // 0..MT*64-1 (MT rows x 64 float4)
    int row  = idx4 >> 6;
    int c4   = idx4 & 63;
    f32x4v xv = *(const f32x4v*)(X + (size_t)(p0 + row) * DIN + c4 * 4);
    ushort4 b;
    b.x = f2bf(xv[0]); b.y = f2bf(xv[1]); b.z = f2bf(xv[2]); b.w = f2bf(xv[3]);
    *(ushort4*)(Xb + row * XLD + c4 * 4) = b;
    unsigned q = cvt2_fp8<false>(xv[0] * xv[0], xv[1] * xv[1], 0u);
    q = cvt2_fp8<true>(xv[2] * xv[2], xv[3] * xv[3], q);
    *(unsigned*)(Xq8 + row * XQLD + c4 * 4) = q;
  }
  __syncthreads();

  const int lane = tid & 63;
  const int wave = tid >> 6;
  const int l16  = lane & 15;
  const int quad = lane >> 4;
  const int qoff = quad * 8;

  const int nrow0 = (wave * 2 + 0) * 16 + l16;   // GEMM2 B rows (dout)
  const int nrow1 = (wave * 2 + 1) * 16 + l16;

  f32x4 acc_mo[NMT][2], acc_vo[NMT][2];
#pragma unroll
  for (int mt = 0; mt < NMT; ++mt)
#pragma unroll
    for (int j = 0; j < 2; ++j) {
      acc_mo[mt][j] = (f32x4){0.f, 0.f, 0.f, 0.f};
      acc_vo[mt][j] = (f32x4){0.f, 0.f, 0.f, 0.f};
    }

#pragma unroll 1
  for (int c = 0; c < 16; ++c) {   // 16 chunks x 64 RFs
    // ---- GEMM1: this wave owns RF rows c*64 + wave*16 + l16 ----
    const ushort_t* w1m = W1mu  + (size_t)(c * 64 + wave * 16 + l16) * DIN + qoff;
    const uchar_t*  w1v = W1var8 + (size_t)(c * 64 + wave * 16 + l16) * DIN + qoff;
    bf16x8 bmu[8]; long long bvr[8];
#pragma unroll
    for (int k = 0; k < 8; ++k) {
      bmu[k] = *(const bf16x8*)(w1m + k * 32);
      bvr[k] = *(const long long*)(w1v + k * 32);
    }
    f32x4 am[NMT], av[NMT];
#pragma unroll
    for (int mt = 0; mt < NMT; ++mt) {
      am[mt] = (f32x4){0.f, 0.f, 0.f, 0.f};
      av[mt] = (f32x4){0.f, 0.f, 0.f, 0.f};
    }
#pragma unroll
    for (int k = 0; k < 8; ++k) {
#pragma unroll
      for (int mt = 0; mt < NMT; ++mt) {
        bf16x8 ax = *(const bf16x8*)(Xb + (mt * 16 + l16) * XLD + k * 32 + qoff);
        long long aq = *(const long long*)(Xq8 + (mt * 16 + l16) * XQLD + k * 32 + qoff);
        am[mt] = __builtin_amdgcn_mfma_f32_16x16x32_bf16(ax, bmu[k], am[mt], 0, 0, 0);
        av[mt] = __builtin_amdgcn_mfma_f32_16x16x32_fp8_fp8(aq, bvr[k], av[mt], 0, 0, 0);
      }
    }

    // ---- preload GEMM2 B (independent of LDS; overlaps moments) ----
    const ushort_t* w2m0 = W2mu + (size_t)nrow0 * NRF + c * 64 + qoff;
    const ushort_t* w2m1 = W2mu + (size_t)nrow1 * NRF + c * 64 + qoff;
    const uchar_t* w2b0 = W2b8 + (size_t)nrow0 * NRF + c * 64 + qoff;
    const uchar_t* w2b1 = W2b8 + (size_t)nrow1 * NRF + c * 64 + qoff;
    const uchar_t* w2v0 = W2var8 + (size_t)nrow0 * NRF + c * 64 + qoff;
    const uchar_t* w2v1 = W2var8 + (size_t)nrow1 * NRF + c * 64 + qoff;
    bf16x8 b2m[2][2]; long long b2b[2][2], b2v[2][2];
#pragma unroll
    for (int k2 = 0; k2 < 2; ++k2) {
      b2m[0][k2] = *(const bf16x8*)(w2m0 + k2 * 32);
      b2m[1][k2] = *(const bf16x8*)(w2m1 + k2 * 32);
      b2b[0][k2] = *(const long long*)(w2b0 + k2 * 32);
      b2b[1][k2] = *(const long long*)(w2b1 + k2 * 32);
      b2v[0][k2] = *(const long long*)(w2v0 + k2 * 32);
      b2v[1][k2] = *(const long long*)(w2v1 + k2 * 32);
    }

    // Barrier A: prior chunk's GEMM2 T-reads complete before overwrite.
    __syncthreads();

    // ---- ReLU moments -> Tm (bf16), Tv8 (fp8 v'), T38 (fp8 m'^2) ----
    const int col = wave * 16 + l16;   // chunk-local column
#pragma unroll
    for (int mt = 0; mt < NMT; ++mt) {
#pragma unroll
      for (int r = 0; r < 4; ++r) {
        float mo, vo;
        relu_moments(am[mt][r], av[mt][r] * 0.00390625f, mo, vo);
        int row = mt * 16 + quad * 4 + r;
        Tm[row * TMLD + col] = f2bf(mo);
        Tv8[row * TVLD + col] = (uchar_t)(cvt2_fp8<false>(vo, vo, 0u) & 0xffu);
        T38[row * TVLD + col] = (uchar_t)(cvt2_fp8<false>(mo * mo, mo * mo, 0u) & 0xffu);
      }
    }
    // Barrier B: T writes visible.
    __syncthreads();

    // ---- GEMM2 over this 64-RF chunk (2 K-steps) ----
#pragma unroll
    for (int k2 = 0; k2 < 2; ++k2) {
#pragma unroll
      for (int mt = 0; mt < NMT; ++mt) {
        int ar = mt * 16 + l16;
        bf16x8 fam = *(const bf16x8*)(Tm + ar * TMLD + k2 * 32 + qoff);
        long long fav = *(const long long*)(Tv8 + ar * TVLD + k2 * 32 + qoff);
        long long f3  = *(const long long*)(T38 + ar * TVLD + k2 * 32 + qoff);
        acc_mo[mt][0] = __builtin_amdgcn_mfma_f32_16x16x32_bf16(fam, b2m[0][k2], acc_mo[mt][0], 0, 0, 0);
        acc_mo[mt][1] = __builtin_amdgcn_mfma_f32_16x16x32_bf16(fam, b2m[1][k2], acc_mo[mt][1], 0, 0, 0);
        acc_vo[mt][0] = __builtin_amdgcn_mfma_f32_16x16x32_fp8_fp8(fav, b2b[0][k2], acc_vo[mt][0], 0, 0, 0);
        acc_vo[mt][1] = __builtin_amdgcn_mfma_f32_16x16x32_fp8_fp8(fav, b2b[1][k2], acc_vo[mt][1], 0, 0, 0);
        acc_vo[mt][0] = __builtin_amdgcn_mfma_f32_16x16x32_fp8_fp8(f3, b2v[0][k2], acc_vo[mt][0], 0, 0, 0);
        acc_vo[mt][1] = __builtin_amdgcn_mfma_f32_16x16x32_fp8_fp8(f3, b2v[1][k2], acc_vo[mt][1], 0, 0, 0);
      }
    }
  }

  // ---- epilogue: precision-weighted scatter (acc_vo carries x256 scale) ----
#pragma unroll
  for (int mt = 0; mt < NMT; ++mt)
#pragma unroll
    for (int j = 0; j < 2; ++j) {
      int dim = (wave * 2 + j) * 16 + l16;
#pragma unroll
      for (int r = 0; r < 4; ++r) {
        int prow = mt * 16 + quad * 4 + r;
        float mo = acc_mo[mt][j][r];
        float vo = fmaf(acc_vo[mt][j][r], 0.00390625f, 1e-6f);
        float prec = fast_rcp(vo);
        size_t o = (size_t)sidx[prow] * DOUT + dim;
        unsafeAtomicAdd(acc_means + o, prec * mo);
        unsafeAtomicAdd(acc_vars + o, prec);
      }
    }
}

// ---------------- kernel 3: finalize ------------------------------------------
__global__ __launch_bounds__(256) void finalize_kernel(float* __restrict__ means,
                                                       float* __restrict__ vars) {
  int i = blockIdx.x * 256 + threadIdx.x;   // covers S*DOUT exactly
  float p  = vars[i];
  float pm = means[i];
  float var = 1.0f / p;
  means[i] = pm * var;
  vars[i]  = var;
}

extern "C" void kernel_launch(void* const* d_in, const int* in_sizes, int n_in,
                              void* d_out, int out_size, void* d_ws, size_t ws_size,
                              hipStream_t stream) {
  const float*    X     = (const float*)d_in[0];
  const unsigned* Xidx  = (const unsigned*)d_in[1];
  const float*    W1mu  = (const float*)d_in[2];
  const float*    W1var = (const float*)d_in[3];
  const float*    W2mu  = (const float*)d_in[4];
  const float*    W2var = (const float*)d_in[5];
  float* out = (float*)d_out;

  ushort_t* w1mu_bf = (ushort_t*)d_ws;                    // 262144 u16
  uchar_t*  w1var8  = (uchar_t*)(w1mu_bf + NRF * DIN);    // 262144 u8
  ushort_t* w2mu_bf = (ushort_t*)(w1var8 + NRF * DIN);    // 131072 u16
  uchar_t*  w2b8    = (uchar_t*)(w2mu_bf + NRF * DOUT);   // 131072 u8
  uchar_t*  w2var8  = w2b8 + NRF * DOUT;                  // 131072 u8
  int* flag = (int*)(w2var8 + NRF * DOUT);

  (void)hipMemsetAsync(d_out, 0, (size_t)out_size * sizeof(float), stream);
  detect_idx_kernel<<<1, 256, 0, stream>>>(Xidx, flag);
  convert_kernel<<<(NRF * DIN) / 4 / 256, 256, 0, stream>>>(
      W1mu, W1var, W2mu, W2var, w1mu_bf, w1var8, w2mu_bf, w2b8, w2var8);
  fused_kernel<<<NWG, 256, 0, stream>>>(
      X, Xidx, w1mu_bf, w1var8, w2mu_bf, w2b8, w2var8, flag,
      out, out + (size_t)SGRP * DOUT);
  finalize_kernel<<<(SGRP * DOUT) / 256, 256, 0, stream>>>(
      out, out + (size_t)SGRP * DOUT);
}

// Round 2
// 860.575 us; speedup vs baseline: 1.1595x; 1.1595x over previous
//
#include <hip/hip_runtime.h>

// DGP-RF embeddings, fused MFMA. Round 10: 3 blocks/CU via MT=48.
// R9 post-mortem: launch_bounds(256,4) => UNIFIED (VGPR+AGPR) cap 128 -> inner
// loop spilled (VGPR_Count=64, per-wave throughput -3.4x). Occupancy was never
// the winner because the win never ran unspilled.
// R8 accounting: Mfma 19.5% + VALU 36% + LDS-pipe ~43% (est) = 98.5% -- the
// three pipes are fully SERIALIZED (barrier phase-lock, 2 blocks/CU).
// R10: MT=48 => LDS 52.0KB => 3 blocks/CU (12 waves/CU) for cross-block phase
// drift; launch_bounds(256,3) => unified cap 170; W1/W2 frag loads moved
// inside k-loops so the allocator picks hoist depth under the cap (no spill).
// Tail: 2731 blocks, last has 32 valid rows (masked staging + atomics).
// Predicted: Occ ~34%, Mfma ~27, VALU ~48, fused ~410-450us.

#define NPTS   131072
#define SGRP   16384
#define DIN    256
#define NRF    1024
#define DOUT   128
#define MT     48            // points per WG  (R10: was 64)
#define NMT    (MT / 16)     // 3 point blocks per WG
#define NWG    ((NPTS + MT - 1) / MT)   // 2731 (last block: 32 valid rows)

#define XLD    264   // bf16 X row stride (x2B = 528B row: 16B-aligned, 2-way banks)
#define XQLD   264   // fp8 x^2 row stride
#define TMLD   72    // bf16 m' row stride (144B row: 16B-aligned)
#define TVLD   72    // fp8 v'/m'^2 row stride

typedef unsigned short ushort_t;
typedef unsigned char  uchar_t;
typedef __attribute__((ext_vector_type(8))) short bf16x8;
typedef __attribute__((ext_vector_type(4))) float f32x4;
typedef __attribute__((ext_vector_type(4))) float f32x4v;

__device__ __forceinline__ unsigned short f2bf(float f) {
  unsigned u = __float_as_uint(f);
  u += 0x7fffu + ((u >> 16) & 1u);   // round-to-nearest-even
  return (unsigned short)(u >> 16);
}

// pack 2 floats -> 2 fp8 e4m3 bytes into (HI? bytes 2,3 : bytes 0,1) of old
template <bool HI>
__device__ __forceinline__ unsigned cvt2_fp8(float a, float b, unsigned old) {
#if __has_builtin(__builtin_amdgcn_cvt_pk_fp8_f32)
  return __builtin_amdgcn_cvt_pk_fp8_f32(a, b, old, HI);
#else
  auto enc = [](float x) -> unsigned {
    if (!(x > 0.00097656f)) return 0u;
    if (x >= 448.f) return 0x7Eu;
    union { float f; unsigned u; } v; v.f = x;
    int e = (int)(v.u >> 23) - 127;
    if (e < -6) { int n = (int)(x * 512.f + 0.5f); return (unsigned)n; }
    v.u += 0x0007FFFFu + ((v.u >> 20) & 1u);
    e = (int)(v.u >> 23) - 127;
    if (e > 8) return 0x7Eu;
    return (unsigned)(((e + 7) << 3) | ((v.u >> 20) & 7u));
  };
  unsigned p = (enc(a) | (enc(b) << 8));
  return HI ? ((old & 0x0000ffffu) | (p << 16)) : ((old & 0xffff0000u) | p);
#endif
}

__device__ __forceinline__ float fast_rcp(float x) {
#if __has_builtin(__builtin_amdgcn_rcpf)
  return __builtin_amdgcn_rcpf(x);
#else
  return 1.0f / x;
#endif
}
__device__ __forceinline__ float fast_rsq(float x) {
#if __has_builtin(__builtin_amdgcn_rsqf)
  return __builtin_amdgcn_rsqf(x);
#else
  return rsqrtf(x);
#endif
}
__device__ __forceinline__ float fast_exp2(float x) {
#if __has_builtin(__builtin_amdgcn_exp2f)
  return __builtin_amdgcn_exp2f(x);
#else
  return exp2f(x);
#endif
}

// Exact Gaussian-ReLU moments (A&S 7.1.26 erf, one shared exp2).
__device__ __forceinline__ void relu_moments(float mu, float v,
                                             float& mo, float& vo) {
  float vpe = v + 1e-8f;
  float rsq = fast_rsq(vpe);
  float s   = vpe * rsq;
  float z   = mu * rsq;
  float E   = fast_exp2(-0.7213475204444817f * z * z);  // exp(-z^2/2)
  float x   = 0.70710678118654752f * fabsf(z);
  float t   = fast_rcp(fmaf(0.3275911f, x, 1.0f));
  float poly = t * fmaf(t, fmaf(t, fmaf(t, fmaf(t, 1.061405429f, -1.453152027f),
                                        1.421413741f), -0.284496736f), 0.254829592f);
  float q   = 0.5f * poly * E;
  float Phi = (z >= 0.0f) ? (1.0f - q) : q;
  float phi = 0.3989422804014327f * E;
  float sphi = s * phi;
  mo = fmaf(mu, Phi, sphi);
  float ey2 = fmaf(fmaf(mu, mu, v), Phi, mu * sphi);
  vo = fmaxf(fmaf(-mo, mo, ey2), 1e-6f);
}

// ---------------- kernel 0: detect whether X_idx is int32 or int64 -------------
__global__ void detect_idx_kernel(const unsigned* __restrict__ raw,
                                  int* __restrict__ flag) {
  __shared__ int any_nz;
  if (threadIdx.x == 0) any_nz = 0;
  __syncthreads();
  if (raw[2 * threadIdx.x + 1] != 0u) atomicOr(&any_nz, 1);
  __syncthreads();
  if (threadIdx.x == 0) *flag = (any_nz == 0) ? 1 : 0;   // 1 => int64
}

// ---------------- kernel 1: convert weights (bf16 mean path, fp8 var path) ----
__global__ __launch_bounds__(256) void convert_kernel(
    const float* __restrict__ W1mu, const float* __restrict__ W1var,
    const float* __restrict__ W2mu, const float* __restrict__ W2var,
    ushort_t* __restrict__ w1mu_bf, uchar_t* __restrict__ w1var8,
    ushort_t* __restrict__ w2mu_bf, uchar_t* __restrict__ w2b8,
    uchar_t* __restrict__ w2var8) {
  int i4 = (blockIdx.x * 256 + threadIdx.x) * 4;   // grid covers 262144
  {
    f32x4v m = *(const f32x4v*)(W1mu + i4);
    ushort4 b; b.x = f2bf(m[0]); b.y = f2bf(m[1]); b.z = f2bf(m[2]); b.w = f2bf(m[3]);
    *(ushort4*)(w1mu_bf + i4) = b;
    f32x4v v = *(const f32x4v*)(W1var + i4);
    unsigned p = cvt2_fp8<false>(v[0] * 256.f, v[1] * 256.f, 0u);
    p = cvt2_fp8<true>(v[2] * 256.f, v[3] * 256.f, p);
    *(unsigned*)(w1var8 + i4) = p;
  }
  if (i4 < NRF * DOUT) {
    f32x4v m = *(const f32x4v*)(W2mu + i4);
    f32x4v v = *(const f32x4v*)(W2var + i4);
    ushort4 b; b.x = f2bf(m[0]); b.y = f2bf(m[1]); b.z = f2bf(m[2]); b.w = f2bf(m[3]);
    *(ushort4*)(w2mu_bf + i4) = b;
    unsigned pb = cvt2_fp8<false>(fmaf(m[0], m[0], v[0]) * 256.f,
                                  fmaf(m[1], m[1], v[1]) * 256.f, 0u);
    pb = cvt2_fp8<true>(fmaf(m[2], m[2], v[2]) * 256.f,
                        fmaf(m[3], m[3], v[3]) * 256.f, pb);
    *(unsigned*)(w2b8 + i4) = pb;
    unsigned pv = cvt2_fp8<false>(v[0] * 256.f, v[1] * 256.f, 0u);
    pv = cvt2_fp8<true>(v[2] * 256.f, v[3] * 256.f, pv);
    *(unsigned*)(w2var8 + i4) = pv;
  }
}

// ---------------- kernel 2: fused DGP-RF block --------------------------------
__global__ __launch_bounds__(256, 3) void fused_kernel(
    const float* __restrict__ X,
    const unsigned* __restrict__ Xidx_raw,
    const ushort_t* __restrict__ W1mu, const uchar_t* __restrict__ W1var8,
    const ushort_t* __restrict__ W2mu, const uchar_t* __restrict__ W2b8,
    const uchar_t* __restrict__ W2var8,
    const int* __restrict__ flag64,
    float* __restrict__ acc_means, float* __restrict__ acc_vars) {
  __shared__ ushort_t Xb[MT * XLD];    // 25.3 KB bf16 x
  __shared__ uchar_t  Xq8[MT * XQLD];  // 12.7 KB fp8 x^2
  __shared__ ushort_t Tm[MT * TMLD];   //  6.9 KB bf16 m'
  __shared__ uchar_t  Tv8[MT * TVLD];  //  3.5 KB fp8 v'
  __shared__ uchar_t  T38[MT * TVLD];  //  3.5 KB fp8 m'^2
  __shared__ int sidx[MT];             // total ~52.0 KB -> 3 blocks/CU

  const int tid = threadIdx.x;
  const int p0  = blockIdx.x * MT;
  const int is64 = *flag64;

  if (tid < MT) {
    int p = p0 + tid;
    sidx[tid] = (p < NPTS) ? (int)(is64 ? Xidx_raw[2 * (size_t)p] : Xidx_raw[p]) : 0;
  }
  // stage X tile: bf16 x and fp8 x^2, converted once here (tail rows -> 0)
#pragma unroll
  for (int i = 0; i < MT / 4; ++i) {
    int idx4 = i * 256 + tid;       // 0..MT*64-1 (MT rows x 64 float4)
    int row  = idx4 >> 6;
    int c4   = idx4 & 63;
    f32x4v xv = (f32x4v){0.f, 0.f, 0.f, 0.f};
    if (p0 + row < NPTS)
      xv = *(const f32x4v*)(X + (size_t)(p0 + row) * DIN + c4 * 4);
    ushort4 b;
    b.x = f2bf(xv[0]); b.y = f2bf(xv[1]); b.z = f2bf(xv[2]); b.w = f2bf(xv[3]);
    *(ushort4*)(Xb + row * XLD + c4 * 4) = b;
    unsigned q = cvt2_fp8<false>(xv[0] * xv[0], xv[1] * xv[1], 0u);
    q = cvt2_fp8<true>(xv[2] * xv[2], xv[3] * xv[3], q);
    *(unsigned*)(Xq8 + row * XQLD + c4 * 4) = q;
  }
  __syncthreads();

  const int lane = tid & 63;
  const int wave = tid >> 6;
  const int l16  = lane & 15;
  const int quad = lane >> 4;
  const int qoff = quad * 8;

  const int nrow0 = (wave * 2 + 0) * 16 + l16;   // GEMM2 B rows (dout)
  const int nrow1 = (wave * 2 + 1) * 16 + l16;

  f32x4 acc_mo[NMT][2], acc_vo[NMT][2];
#pragma unroll
  for (int mt = 0; mt < NMT; ++mt)
#pragma unroll
    for (int j = 0; j < 2; ++j) {
      acc_mo[mt][j] = (f32x4){0.f, 0.f, 0.f, 0.f};
      acc_vo[mt][j] = (f32x4){0.f, 0.f, 0.f, 0.f};
    }

#pragma unroll 1
  for (int c = 0; c < 16; ++c) {   // 16 chunks x 64 RFs
    // ---- GEMM1: this wave owns RF rows c*64 + wave*16 + l16 ----
    // W1 frag loads are INSIDE the k-loop: under the unified 170-reg cap the
    // allocator picks the hoist depth (R9 lesson: don't hold 48 regs across).
    const ushort_t* w1m = W1mu  + (size_t)(c * 64 + wave * 16 + l16) * DIN + qoff;
    const uchar_t*  w1v = W1var8 + (size_t)(c * 64 + wave * 16 + l16) * DIN + qoff;
    f32x4 am[NMT], av[NMT];
#pragma unroll
    for (int mt = 0; mt < NMT; ++mt) {
      am[mt] = (f32x4){0.f, 0.f, 0.f, 0.f};
      av[mt] = (f32x4){0.f, 0.f, 0.f, 0.f};
    }
#pragma unroll
    for (int k = 0; k < 8; ++k) {
      bf16x8 bmu = *(const bf16x8*)(w1m + k * 32);
      long long bvr = *(const long long*)(w1v + k * 32);
#pragma unroll
      for (int mt = 0; mt < NMT; ++mt) {
        bf16x8 ax = *(const bf16x8*)(Xb + (mt * 16 + l16) * XLD + k * 32 + qoff);
        long long aq = *(const long long*)(Xq8 + (mt * 16 + l16) * XQLD + k * 32 + qoff);
        am[mt] = __builtin_amdgcn_mfma_f32_16x16x32_bf16(ax, bmu, am[mt], 0, 0, 0);
        av[mt] = __builtin_amdgcn_mfma_f32_16x16x32_fp8_fp8(aq, bvr, av[mt], 0, 0, 0);
      }
    }

    // Barrier A: prior chunk's GEMM2 T-reads complete before overwrite.
    __syncthreads();

    // ---- ReLU moments -> Tm (bf16), Tv8 (fp8 v'), T38 (fp8 m'^2) ----
    const int col = wave * 16 + l16;   // chunk-local column
#pragma unroll
    for (int mt = 0; mt < NMT; ++mt) {
#pragma unroll
      for (int r = 0; r < 4; ++r) {
        float mo, vo;
        relu_moments(am[mt][r], av[mt][r] * 0.00390625f, mo, vo);
        int row = mt * 16 + quad * 4 + r;
        Tm[row * TMLD + col] = f2bf(mo);
        Tv8[row * TVLD + col] = (uchar_t)(cvt2_fp8<false>(vo, vo, 0u) & 0xffu);
        T38[row * TVLD + col] = (uchar_t)(cvt2_fp8<false>(mo * mo, mo * mo, 0u) & 0xffu);
      }
    }
    // Barrier B: T writes visible.
    __syncthreads();

    // ---- GEMM2 over this 64-RF chunk (2 K-steps) ----
#pragma unroll
    for (int k2 = 0; k2 < 2; ++k2) {
      bf16x8 b2m0 = *(const bf16x8*)(W2mu + (size_t)nrow0 * NRF + c * 64 + qoff + k2 * 32);
      bf16x8 b2m1 = *(const bf16x8*)(W2mu + (size_t)nrow1 * NRF + c * 64 + qoff + k2 * 32);
      long long b2b0 = *(const long long*)(W2b8 + (size_t)nrow0 * NRF + c * 64 + qoff + k2 * 32);
      long long b2b1 = *(const long long*)(W2b8 + (size_t)nrow1 * NRF + c * 64 + qoff + k2 * 32);
      long long b2v0 = *(const long long*)(W2var8 + (size_t)nrow0 * NRF + c * 64 + qoff + k2 * 32);
      long long b2v1 = *(const long long*)(W2var8 + (size_t)nrow1 * NRF + c * 64 + qoff + k2 * 32);
#pragma unroll
      for (int mt = 0; mt < NMT; ++mt) {
        int ar = mt * 16 + l16;
        bf16x8 fam = *(const bf16x8*)(Tm + ar * TMLD + k2 * 32 + qoff);
        long long fav = *(const long long*)(Tv8 + ar * TVLD + k2 * 32 + qoff);
        long long f3  = *(const long long*)(T38 + ar * TVLD + k2 * 32 + qoff);
        acc_mo[mt][0] = __builtin_amdgcn_mfma_f32_16x16x32_bf16(fam, b2m0, acc_mo[mt][0], 0, 0, 0);
        acc_mo[mt][1] = __builtin_amdgcn_mfma_f32_16x16x32_bf16(fam, b2m1, acc_mo[mt][1], 0, 0, 0);
        acc_vo[mt][0] = __builtin_amdgcn_mfma_f32_16x16x32_fp8_fp8(fav, b2b0, acc_vo[mt][0], 0, 0, 0);
        acc_vo[mt][1] = __builtin_amdgcn_mfma_f32_16x16x32_fp8_fp8(fav, b2b1, acc_vo[mt][1], 0, 0, 0);
        acc_vo[mt][0] = __builtin_amdgcn_mfma_f32_16x16x32_fp8_fp8(f3, b2v0, acc_vo[mt][0], 0, 0, 0);
        acc_vo[mt][1] = __builtin_amdgcn_mfma_f32_16x16x32_fp8_fp8(f3, b2v1, acc_vo[mt][1], 0, 0, 0);
      }
    }
  }

  // ---- epilogue: precision-weighted scatter (acc_vo carries x256 scale) ----
#pragma unroll
  for (int mt = 0; mt < NMT; ++mt)
#pragma unroll
    for (int j = 0; j < 2; ++j) {
      int dim = (wave * 2 + j) * 16 + l16;
#pragma unroll
      for (int r = 0; r < 4; ++r) {
        int prow = mt * 16 + quad * 4 + r;
        if (p0 + prow < NPTS) {
          float mo = acc_mo[mt][j][r];
          float vo = fmaf(acc_vo[mt][j][r], 0.00390625f, 1e-6f);
          float prec = fast_rcp(vo);
          size_t o = (size_t)sidx[prow] * DOUT + dim;
          unsafeAtomicAdd(acc_means + o, prec * mo);
          unsafeAtomicAdd(acc_vars + o, prec);
        }
      }
    }
}

// ---------------- kernel 3: finalize ------------------------------------------
__global__ __launch_bounds__(256) void finalize_kernel(float* __restrict__ means,
                                                       float* __restrict__ vars) {
  int i = blockIdx.x * 256 + threadIdx.x;   // covers S*DOUT exactly
  float p  = vars[i];
  float pm = means[i];
  float var = 1.0f / p;
  means[i] = pm * var;
  vars[i]  = var;
}

extern "C" void kernel_launch(void* const* d_in, const int* in_sizes, int n_in,
                              void* d_out, int out_size, void* d_ws, size_t ws_size,
                              hipStream_t stream) {
  const float*    X     = (const float*)d_in[0];
  const unsigned* Xidx  = (const unsigned*)d_in[1];
  const float*    W1mu  = (const float*)d_in[2];
  const float*    W1var = (const float*)d_in[3];
  const float*    W2mu  = (const float*)d_in[4];
  const float*    W2var = (const float*)d_in[5];
  float* out = (float*)d_out;

  ushort_t* w1mu_bf = (ushort_t*)d_ws;                    // 262144 u16
  uchar_t*  w1var8  = (uchar_t*)(w1mu_bf + NRF * DIN);    // 262144 u8
  ushort_t* w2mu_bf = (ushort_t*)(w1var8 + NRF * DIN);    // 131072 u16
  uchar_t*  w2b8    = (uchar_t*)(w2mu_bf + NRF * DOUT);   // 131072 u8
  uchar_t*  w2var8  = w2b8 + NRF * DOUT;                  // 131072 u8
  int* flag = (int*)(w2var8 + NRF * DOUT);

  (void)hipMemsetAsync(d_out, 0, (size_t)out_size * sizeof(float), stream);
  detect_idx_kernel<<<1, 256, 0, stream>>>(Xidx, flag);
  convert_kernel<<<(NRF * DIN) / 4 / 256, 256, 0, stream>>>(
      W1mu, W1var, W2mu, W2var, w1mu_bf, w1var8, w2mu_bf, w2b8, w2var8);
  fused_kernel<<<NWG, 256, 0, stream>>>(
      X, Xidx, w1mu_bf, w1var8, w2mu_bf, w2b8, w2var8, flag,
      out, out + (size_t)SGRP * DOUT);
  finalize_kernel<<<(SGRP * DOUT) / 256, 256, 0, stream>>>(
      out, out + (size_t)SGRP * DOUT);
}

// Round 3
// 756.556 us; speedup vs baseline: 1.3190x; 1.1375x over previous
//
#include <hip/hip_runtime.h>

// DGP-RF embeddings, fused MFMA. Round 11: intra-wave chunk pipelining.
// R9/R10 post-mortem: BOTH occupancy pushes regressed (908/750us vs R8 529us)
// with the same signature -- register caps forced W1/W2 frag loads into the
// k-loop, exposing ~200cy L2 latency per step. Residency cannot buy back
// per-wave ILP. R8 (MT=64, 2blk/CU, hoisted frags) is the right residency.
// R8's real problem: Mfma 19.5 + VALU 36 + LDS ~43 == ~100% -> pipes run
// SERIALLY because moments(c) depends on GEMM1(c) just computed.
// R11: double-buffer GEMM1 accs (am2/av2); compute GEMM1(c+1) in the SAME
// barrier region as moments(c) so the scheduler interleaves MFMA+LDS with
// VALU (independent: GEMM1 reads only immutable Xb/Xq8 + W1). Live regs
// ~230 < 256 budget at 2 blk/CU -- launch_bounds stays (256,2).
// Predicted: Mfma ~30, VALU ~55, Occ ~23 (unchanged by design),
// VGPR 150-230, conflicts 2.1e7 unchanged, fused ~370-420us.

#define NPTS   131072
#define SGRP   16384
#define DIN    256
#define NRF    1024
#define DOUT   128
#define MT     64            // points per WG (back to R8)
#define NWG    (NPTS / MT)   // 2048

#define XLD    264   // bf16 X row stride
#define XQLD   264   // fp8 x^2 row stride
#define TMLD   72    // bf16 m' row stride
#define TVLD   72    // fp8 v'/m'^2 row stride

typedef unsigned short ushort_t;
typedef unsigned char  uchar_t;
typedef __attribute__((ext_vector_type(8))) short bf16x8;
typedef __attribute__((ext_vector_type(4))) float f32x4;
typedef __attribute__((ext_vector_type(4))) float f32x4v;

__device__ __forceinline__ unsigned short f2bf(float f) {
  unsigned u = __float_as_uint(f);
  u += 0x7fffu + ((u >> 16) & 1u);   // round-to-nearest-even
  return (unsigned short)(u >> 16);
}

// pack 2 floats -> 2 fp8 e4m3 bytes into (HI? bytes 2,3 : bytes 0,1) of old
template <bool HI>
__device__ __forceinline__ unsigned cvt2_fp8(float a, float b, unsigned old) {
#if __has_builtin(__builtin_amdgcn_cvt_pk_fp8_f32)
  return __builtin_amdgcn_cvt_pk_fp8_f32(a, b, old, HI);
#else
  auto enc = [](float x) -> unsigned {
    if (!(x > 0.00097656f)) return 0u;
    if (x >= 448.f) return 0x7Eu;
    union { float f; unsigned u; } v; v.f = x;
    int e = (int)(v.u >> 23) - 127;
    if (e < -6) { int n = (int)(x * 512.f + 0.5f); return (unsigned)n; }
    v.u += 0x0007FFFFu + ((v.u >> 20) & 1u);
    e = (int)(v.u >> 23) - 127;
    if (e > 8) return 0x7Eu;
    return (unsigned)(((e + 7) << 3) | ((v.u >> 20) & 7u));
  };
  unsigned p = (enc(a) | (enc(b) << 8));
  return HI ? ((old & 0x0000ffffu) | (p << 16)) : ((old & 0xffff0000u) | p);
#endif
}

__device__ __forceinline__ float fast_rcp(float x) {
#if __has_builtin(__builtin_amdgcn_rcpf)
  return __builtin_amdgcn_rcpf(x);
#else
  return 1.0f / x;
#endif
}
__device__ __forceinline__ float fast_rsq(float x) {
#if __has_builtin(__builtin_amdgcn_rsqf)
  return __builtin_amdgcn_rsqf(x);
#else
  return rsqrtf(x);
#endif
}
__device__ __forceinline__ float fast_exp2(float x) {
#if __has_builtin(__builtin_amdgcn_exp2f)
  return __builtin_amdgcn_exp2f(x);
#else
  return exp2f(x);
#endif
}

// Exact Gaussian-ReLU moments (A&S 7.1.26 erf, one shared exp2).
__device__ __forceinline__ void relu_moments(float mu, float v,
                                             float& mo, float& vo) {
  float vpe = v + 1e-8f;
  float rsq = fast_rsq(vpe);
  float s   = vpe * rsq;
  float z   = mu * rsq;
  float E   = fast_exp2(-0.7213475204444817f * z * z);  // exp(-z^2/2)
  float x   = 0.70710678118654752f * fabsf(z);
  float t   = fast_rcp(fmaf(0.3275911f, x, 1.0f));
  float poly = t * fmaf(t, fmaf(t, fmaf(t, fmaf(t, 1.061405429f, -1.453152027f),
                                        1.421413741f), -0.284496736f), 0.254829592f);
  float q   = 0.5f * poly * E;
  float Phi = (z >= 0.0f) ? (1.0f - q) : q;
  float phi = 0.3989422804014327f * E;
  float sphi = s * phi;
  mo = fmaf(mu, Phi, sphi);
  float ey2 = fmaf(fmaf(mu, mu, v), Phi, mu * sphi);
  vo = fmaxf(fmaf(-mo, mo, ey2), 1e-6f);
}

// ---------------- kernel 0: detect whether X_idx is int32 or int64 -------------
__global__ void detect_idx_kernel(const unsigned* __restrict__ raw,
                                  int* __restrict__ flag) {
  __shared__ int any_nz;
  if (threadIdx.x == 0) any_nz = 0;
  __syncthreads();
  if (raw[2 * threadIdx.x + 1] != 0u) atomicOr(&any_nz, 1);
  __syncthreads();
  if (threadIdx.x == 0) *flag = (any_nz == 0) ? 1 : 0;   // 1 => int64
}

// ---------------- kernel 1: convert weights (bf16 mean path, fp8 var path) ----
__global__ __launch_bounds__(256) void convert_kernel(
    const float* __restrict__ W1mu, const float* __restrict__ W1var,
    const float* __restrict__ W2mu, const float* __restrict__ W2var,
    ushort_t* __restrict__ w1mu_bf, uchar_t* __restrict__ w1var8,
    ushort_t* __restrict__ w2mu_bf, uchar_t* __restrict__ w2b8,
    uchar_t* __restrict__ w2var8) {
  int i4 = (blockIdx.x * 256 + threadIdx.x) * 4;   // grid covers 262144
  {
    f32x4v m = *(const f32x4v*)(W1mu + i4);
    ushort4 b; b.x = f2bf(m[0]); b.y = f2bf(m[1]); b.z = f2bf(m[2]); b.w = f2bf(m[3]);
    *(ushort4*)(w1mu_bf + i4) = b;
    f32x4v v = *(const f32x4v*)(W1var + i4);
    unsigned p = cvt2_fp8<false>(v[0] * 256.f, v[1] * 256.f, 0u);
    p = cvt2_fp8<true>(v[2] * 256.f, v[3] * 256.f, p);
    *(unsigned*)(w1var8 + i4) = p;
  }
  if (i4 < NRF * DOUT) {
    f32x4v m = *(const f32x4v*)(W2mu + i4);
    f32x4v v = *(const f32x4v*)(W2var + i4);
    ushort4 b; b.x = f2bf(m[0]); b.y = f2bf(m[1]); b.z = f2bf(m[2]); b.w = f2bf(m[3]);
    *(ushort4*)(w2mu_bf + i4) = b;
    unsigned pb = cvt2_fp8<false>(fmaf(m[0], m[0], v[0]) * 256.f,
                                  fmaf(m[1], m[1], v[1]) * 256.f, 0u);
    pb = cvt2_fp8<true>(fmaf(m[2], m[2], v[2]) * 256.f,
                        fmaf(m[3], m[3], v[3]) * 256.f, pb);
    *(unsigned*)(w2b8 + i4) = pb;
    unsigned pv = cvt2_fp8<false>(v[0] * 256.f, v[1] * 256.f, 0u);
    pv = cvt2_fp8<true>(v[2] * 256.f, v[3] * 256.f, pv);
    *(unsigned*)(w2var8 + i4) = pv;
  }
}

// ---------------- kernel 2: fused DGP-RF block --------------------------------
__global__ __launch_bounds__(256, 2) void fused_kernel(
    const float* __restrict__ X,
    const unsigned* __restrict__ Xidx_raw,
    const ushort_t* __restrict__ W1mu, const uchar_t* __restrict__ W1var8,
    const ushort_t* __restrict__ W2mu, const uchar_t* __restrict__ W2b8,
    const uchar_t* __restrict__ W2var8,
    const int* __restrict__ flag64,
    float* __restrict__ acc_means, float* __restrict__ acc_vars) {
  __shared__ ushort_t Xb[MT * XLD];    // 33.8 KB bf16 x
  __shared__ uchar_t  Xq8[MT * XQLD];  // 16.9 KB fp8 x^2
  __shared__ ushort_t Tm[MT * TMLD];   //  9.2 KB bf16 m'
  __shared__ uchar_t  Tv8[MT * TVLD];  //  4.6 KB fp8 v'
  __shared__ uchar_t  T38[MT * TVLD];  //  4.6 KB fp8 m'^2
  __shared__ int sidx[MT];

  const int tid = threadIdx.x;
  const int p0  = blockIdx.x * MT;
  const int is64 = *flag64;

  if (tid < MT) {
    int p = p0 + tid;
    sidx[tid] = (int)(is64 ? Xidx_raw[2 * (size_t)p] : Xidx_raw[p]);
  }
  // stage X tile: bf16 x and fp8 x^2, converted once here
#pragma unroll
  for (int i = 0; i < 16; ++i) {
    int idx4 = i * 256 + tid;       // 0..4095 (64 rows x 64 float4)
    int row  = idx4 >> 6;
    int c4   = idx4 & 63;
    f32x4v xv = *(const f32x4v*)(X + (size_t)(p0 + row) * DIN + c4 * 4);
    ushort4 b;
    b.x = f2bf(xv[0]); b.y = f2bf(xv[1]); b.z = f2bf(xv[2]); b.w = f2bf(xv[3]);
    *(ushort4*)(Xb + row * XLD + c4 * 4) = b;
    unsigned q = cvt2_fp8<false>(xv[0] * xv[0], xv[1] * xv[1], 0u);
    q = cvt2_fp8<true>(xv[2] * xv[2], xv[3] * xv[3], q);
    *(unsigned*)(Xq8 + row * XQLD + c4 * 4) = q;
  }
  __syncthreads();

  const int lane = tid & 63;
  const int wave = tid >> 6;
  const int l16  = lane & 15;
  const int quad = lane >> 4;
  const int qoff = quad * 8;

  const int nrow0 = (wave * 2 + 0) * 16 + l16;   // GEMM2 B rows (dout)
  const int nrow1 = (wave * 2 + 1) * 16 + l16;

  f32x4 acc_mo[4][2], acc_vo[4][2];
#pragma unroll
  for (int mt = 0; mt < 4; ++mt)
#pragma unroll
    for (int j = 0; j < 2; ++j) {
      acc_mo[mt][j] = (f32x4){0.f, 0.f, 0.f, 0.f};
      acc_vo[mt][j] = (f32x4){0.f, 0.f, 0.f, 0.f};
    }

  // ---- GEMM1 pipeline registers: am/av = chunk c (ready), am2/av2 = c+1 ----
  f32x4 am[4], av[4], am2[4], av2[4];

  // prologue: GEMM1 for chunk 0
  {
    const ushort_t* w1m = W1mu  + (size_t)(wave * 16 + l16) * DIN + qoff;
    const uchar_t*  w1v = W1var8 + (size_t)(wave * 16 + l16) * DIN + qoff;
    bf16x8 bmu[8]; long long bvr[8];
#pragma unroll
    for (int k = 0; k < 8; ++k) {
      bmu[k] = *(const bf16x8*)(w1m + k * 32);
      bvr[k] = *(const long long*)(w1v + k * 32);
    }
#pragma unroll
    for (int mt = 0; mt < 4; ++mt) {
      am[mt] = (f32x4){0.f, 0.f, 0.f, 0.f};
      av[mt] = (f32x4){0.f, 0.f, 0.f, 0.f};
    }
#pragma unroll
    for (int k = 0; k < 8; ++k) {
#pragma unroll
      for (int mt = 0; mt < 4; ++mt) {
        bf16x8 ax = *(const bf16x8*)(Xb + (mt * 16 + l16) * XLD + k * 32 + qoff);
        long long aq = *(const long long*)(Xq8 + (mt * 16 + l16) * XQLD + k * 32 + qoff);
        am[mt] = __builtin_amdgcn_mfma_f32_16x16x32_bf16(ax, bmu[k], am[mt], 0, 0, 0);
        av[mt] = __builtin_amdgcn_mfma_f32_16x16x32_fp8_fp8(aq, bvr[k], av[mt], 0, 0, 0);
      }
    }
  }

#pragma unroll 1
  for (int c = 0; c < 16; ++c) {   // 16 chunks x 64 RFs
    // ---- preload GEMM2 B for chunk c (global; consumed after barrier B) ----
    const ushort_t* w2m0 = W2mu + (size_t)nrow0 * NRF + c * 64 + qoff;
    const ushort_t* w2m1 = W2mu + (size_t)nrow1 * NRF + c * 64 + qoff;
    const uchar_t* w2b0 = W2b8 + (size_t)nrow0 * NRF + c * 64 + qoff;
    const uchar_t* w2b1 = W2b8 + (size_t)nrow1 * NRF + c * 64 + qoff;
    const uchar_t* w2v0 = W2var8 + (size_t)nrow0 * NRF + c * 64 + qoff;
    const uchar_t* w2v1 = W2var8 + (size_t)nrow1 * NRF + c * 64 + qoff;
    bf16x8 b2m[2][2]; long long b2b[2][2], b2v[2][2];
#pragma unroll
    for (int k2 = 0; k2 < 2; ++k2) {
      b2m[0][k2] = *(const bf16x8*)(w2m0 + k2 * 32);
      b2m[1][k2] = *(const bf16x8*)(w2m1 + k2 * 32);
      b2b[0][k2] = *(const long long*)(w2b0 + k2 * 32);
      b2b[1][k2] = *(const long long*)(w2b1 + k2 * 32);
      b2v[0][k2] = *(const long long*)(w2v0 + k2 * 32);
      b2v[1][k2] = *(const long long*)(w2v1 + k2 * 32);
    }

    // Barrier A: prior chunk's GEMM2 T-reads complete before overwrite.
    __syncthreads();

    // ---- REGION: GEMM1(c+1) [MFMA+LDS] + moments(c) [VALU] interleave ----
    // GEMM1(c+1) is independent (immutable Xb/Xq8, W1) -> scheduler mixes
    // its MFMA/LDS issues with the moments VALU chain. This is the R11 lever.
    if (c < 15) {
      const ushort_t* w1m = W1mu  + (size_t)((c + 1) * 64 + wave * 16 + l16) * DIN + qoff;
      const uchar_t*  w1v = W1var8 + (size_t)((c + 1) * 64 + wave * 16 + l16) * DIN + qoff;
      bf16x8 bmu[8]; long long bvr[8];
#pragma unroll
      for (int k = 0; k < 8; ++k) {
        bmu[k] = *(const bf16x8*)(w1m + k * 32);
        bvr[k] = *(const long long*)(w1v + k * 32);
      }
#pragma unroll
      for (int mt = 0; mt < 4; ++mt) {
        am2[mt] = (f32x4){0.f, 0.f, 0.f, 0.f};
        av2[mt] = (f32x4){0.f, 0.f, 0.f, 0.f};
      }
#pragma unroll
      for (int k = 0; k < 8; ++k) {
#pragma unroll
        for (int mt = 0; mt < 4; ++mt) {
          bf16x8 ax = *(const bf16x8*)(Xb + (mt * 16 + l16) * XLD + k * 32 + qoff);
          long long aq = *(const long long*)(Xq8 + (mt * 16 + l16) * XQLD + k * 32 + qoff);
          am2[mt] = __builtin_amdgcn_mfma_f32_16x16x32_bf16(ax, bmu[k], am2[mt], 0, 0, 0);
          av2[mt] = __builtin_amdgcn_mfma_f32_16x16x32_fp8_fp8(aq, bvr[k], av2[mt], 0, 0, 0);
        }
      }
    }

    // ---- ReLU moments(c) -> Tm (bf16), Tv8 (fp8 v'), T38 (fp8 m'^2) ----
    const int col = wave * 16 + l16;   // chunk-local column
#pragma unroll
    for (int mt = 0; mt < 4; ++mt) {
#pragma unroll
      for (int r = 0; r < 4; ++r) {
        float mo, vo;
        relu_moments(am[mt][r], av[mt][r] * 0.00390625f, mo, vo);
        int row = mt * 16 + quad * 4 + r;
        Tm[row * TMLD + col] = f2bf(mo);
        Tv8[row * TVLD + col] = (uchar_t)(cvt2_fp8<false>(vo, vo, 0u) & 0xffu);
        T38[row * TVLD + col] = (uchar_t)(cvt2_fp8<false>(mo * mo, mo * mo, 0u) & 0xffu);
      }
    }
    // Barrier B: T writes visible.
    __syncthreads();

    // ---- GEMM2 over this 64-RF chunk (2 K-steps) ----
#pragma unroll
    for (int k2 = 0; k2 < 2; ++k2) {
#pragma unroll
      for (int mt = 0; mt < 4; ++mt) {
        int ar = mt * 16 + l16;
        bf16x8 fam = *(const bf16x8*)(Tm + ar * TMLD + k2 * 32 + qoff);
        long long fav = *(const long long*)(Tv8 + ar * TVLD + k2 * 32 + qoff);
        long long f3  = *(const long long*)(T38 + ar * TVLD + k2 * 32 + qoff);
        acc_mo[mt][0] = __builtin_amdgcn_mfma_f32_16x16x32_bf16(fam, b2m[0][k2], acc_mo[mt][0], 0, 0, 0);
        acc_mo[mt][1] = __builtin_amdgcn_mfma_f32_16x16x32_bf16(fam, b2m[1][k2], acc_mo[mt][1], 0, 0, 0);
        acc_vo[mt][0] = __builtin_amdgcn_mfma_f32_16x16x32_fp8_fp8(fav, b2b[0][k2], acc_vo[mt][0], 0, 0, 0);
        acc_vo[mt][1] = __builtin_amdgcn_mfma_f32_16x16x32_fp8_fp8(fav, b2b[1][k2], acc_vo[mt][1], 0, 0, 0);
        acc_vo[mt][0] = __builtin_amdgcn_mfma_f32_16x16x32_fp8_fp8(f3, b2v[0][k2], acc_vo[mt][0], 0, 0, 0);
        acc_vo[mt][1] = __builtin_amdgcn_mfma_f32_16x16x32_fp8_fp8(f3, b2v[1][k2], acc_vo[mt][1], 0, 0, 0);
      }
    }

    // ---- rotate pipeline registers ----
#pragma unroll
    for (int mt = 0; mt < 4; ++mt) {
      am[mt] = am2[mt];
      av[mt] = av2[mt];
    }
  }

  // ---- epilogue: precision-weighted scatter (acc_vo carries x256 scale) ----
#pragma unroll
  for (int mt = 0; mt < 4; ++mt)
#pragma unroll
    for (int j = 0; j < 2; ++j) {
      int dim = (wave * 2 + j) * 16 + l16;
#pragma unroll
      for (int r = 0; r < 4; ++r) {
        int prow = mt * 16 + quad * 4 + r;
        float mo = acc_mo[mt][j][r];
        float vo = fmaf(acc_vo[mt][j][r], 0.00390625f, 1e-6f);
        float prec = fast_rcp(vo);
        size_t o = (size_t)sidx[prow] * DOUT + dim;
        unsafeAtomicAdd(acc_means + o, prec * mo);
        unsafeAtomicAdd(acc_vars + o, prec);
      }
    }
}

// ---------------- kernel 3: finalize ------------------------------------------
__global__ __launch_bounds__(256) void finalize_kernel(float* __restrict__ means,
                                                       float* __restrict__ vars) {
  int i = blockIdx.x * 256 + threadIdx.x;   // covers S*DOUT exactly
  float p  = vars[i];
  float pm = means[i];
  float var = 1.0f / p;
  means[i] = pm * var;
  vars[i]  = var;
}

extern "C" void kernel_launch(void* const* d_in, const int* in_sizes, int n_in,
                              void* d_out, int out_size, void* d_ws, size_t ws_size,
                              hipStream_t stream) {
  const float*    X     = (const float*)d_in[0];
  const unsigned* Xidx  = (const unsigned*)d_in[1];
  const float*    W1mu  = (const float*)d_in[2];
  const float*    W1var = (const float*)d_in[3];
  const float*    W2mu  = (const float*)d_in[4];
  const float*    W2var = (const float*)d_in[5];
  float* out = (float*)d_out;

  ushort_t* w1mu_bf = (ushort_t*)d_ws;                    // 262144 u16
  uchar_t*  w1var8  = (uchar_t*)(w1mu_bf + NRF * DIN);    // 262144 u8
  ushort_t* w2mu_bf = (ushort_t*)(w1var8 + NRF * DIN);    // 131072 u16
  uchar_t*  w2b8    = (uchar_t*)(w2mu_bf + NRF * DOUT);   // 131072 u8
  uchar_t*  w2var8  = w2b8 + NRF * DOUT;                  // 131072 u8
  int* flag = (int*)(w2var8 + NRF * DOUT);

  (void)hipMemsetAsync(d_out, 0, (size_t)out_size * sizeof(float), stream);
  detect_idx_kernel<<<1, 256, 0, stream>>>(Xidx, flag);
  convert_kernel<<<(NRF * DIN) / 4 / 256, 256, 0, stream>>>(
      W1mu, W1var, W2mu, W2var, w1mu_bf, w1var8, w2mu_bf, w2b8, w2var8);
  fused_kernel<<<NWG, 256, 0, stream>>>(
      X, Xidx, w1mu_bf, w1var8, w2mu_bf, w2b8, w2var8, flag,
      out, out + (size_t)SGRP * DOUT);
  finalize_kernel<<<(SGRP * DOUT) / 256, 256, 0, stream>>>(
      out, out + (size_t)SGRP * DOUT);
}